// Round 6
// baseline (313.810 us; speedup 1.0000x reference)
//
#include <hip/hip_runtime.h>
#include <math.h>

#define E 288
#define NSEQ 2048
#define BATCH 4
#define NH 8
#define HD 36
#define BH (BATCH * NH)      // 32
#define ROWS (BATCH * NSEQ)  // 8192

typedef _Float16 half8_t __attribute__((ext_vector_type(8)));
typedef _Float16 half4_t __attribute__((ext_vector_type(4)));
typedef float f32x4 __attribute__((ext_vector_type(4)));
typedef int i32x4 __attribute__((ext_vector_type(4)));

// ===========================================================================
// split_w: W (fp32, [k][n]) -> transposed fp16: whalf[m][n*E + k]
// ===========================================================================
__global__ __launch_bounds__(256) void split_w_kernel(
    const float* __restrict__ Wq, const float* __restrict__ Wk,
    const float* __restrict__ Wv, const float* __restrict__ Wo,
    _Float16* __restrict__ whalf) {
  const int idx = blockIdx.x * 256 + threadIdx.x;  // 0 .. 4*E*E-1
  const int m = idx / (E * E);
  const int rem = idx - m * (E * E);
  const int k = rem / E, n = rem - k * E;
  const float* W = (m == 0) ? Wq : (m == 1) ? Wk : (m == 2) ? Wv : Wo;
  whalf[(size_t)m * (E * E) + n * E + k] = (_Float16)W[rem];
}

// ===========================================================================
// QKV projection, single-term fp16 MFMA. Tile 128x96, K chunks of 32,
// register prefetch across barriers.
// mode 0/1 -> q16/k16 [bh][n][64]  (cols 36..63 pre-zeroed by memset)
// mode 2   -> v16t [bh][48][n']    (transposed, pi-interleaved key order;
//                                   rows 36..47 pre-zeroed by memset)
// ===========================================================================
#define PM 128
#define PN 96
#define LDA 40  // LDS row stride in halfs

struct QKVArgs {
  const float* x[3];
  const _Float16* w[3];
  const float* bias[3];
  _Float16* out[3];
};

__global__ __launch_bounds__(256, 4) void proj_qkv_kernel(QKVArgs A) {
  __shared__ __align__(16) _Float16 a_h[PM * LDA];
  __shared__ __align__(16) _Float16 w_h[PN * LDA];

  const int tid = threadIdx.x;
  const int lane = tid & 63, wv = tid >> 6;
  const int quad = lane >> 4, l15 = lane & 15;
  const int mode = blockIdx.z;
  const float* __restrict__ x = A.x[mode];
  const _Float16* __restrict__ wh = A.w[mode];
  const int row0 = blockIdx.x * PM, col0 = blockIdx.y * PN;

  f32x4 acc[2][6];
#pragma unroll
  for (int t = 0; t < 2; ++t)
#pragma unroll
    for (int nt = 0; nt < 6; ++nt) acc[t][nt] = (f32x4){0.f, 0.f, 0.f, 0.f};

  float4 apre[4];
  i32x4 wpre[2];
#pragma unroll
  for (int iu = 0; iu < 4; ++iu) {
    const int i = tid + 256 * iu, r = i >> 3, c4 = i & 7;
    apre[iu] = *(const float4*)&x[(size_t)(row0 + r) * E + c4 * 4];
  }
  {
    const int n = tid >> 2, qd = tid & 3;
    wpre[0] = *(const i32x4*)&wh[(size_t)(col0 + n) * E + qd * 8];
    if (tid < 128) {
      const int i = tid + 256, n2 = i >> 2, q2 = i & 3;
      wpre[1] = *(const i32x4*)&wh[(size_t)(col0 + n2) * E + q2 * 8];
    }
  }

  for (int kk = 0; kk < E; kk += 32) {
    __syncthreads();
#pragma unroll
    for (int iu = 0; iu < 4; ++iu) {
      const int i = tid + 256 * iu, r = i >> 3, c4 = i & 7;
      half4_t hv = {(_Float16)apre[iu].x, (_Float16)apre[iu].y,
                    (_Float16)apre[iu].z, (_Float16)apre[iu].w};
      *(half4_t*)&a_h[r * LDA + c4 * 4] = hv;
    }
    {
      const int n = tid >> 2, qd = tid & 3;
      *(i32x4*)&w_h[n * LDA + qd * 8] = wpre[0];
      if (tid < 128) {
        const int i = tid + 256, n2 = i >> 2, q2 = i & 3;
        *(i32x4*)&w_h[n2 * LDA + q2 * 8] = wpre[1];
      }
    }
    if (kk + 32 < E) {
#pragma unroll
      for (int iu = 0; iu < 4; ++iu) {
        const int i = tid + 256 * iu, r = i >> 3, c4 = i & 7;
        apre[iu] = *(const float4*)&x[(size_t)(row0 + r) * E + kk + 32 + c4 * 4];
      }
      const int n = tid >> 2, qd = tid & 3;
      wpre[0] = *(const i32x4*)&wh[(size_t)(col0 + n) * E + kk + 32 + qd * 8];
      if (tid < 128) {
        const int i = tid + 256, n2 = i >> 2, q2 = i & 3;
        wpre[1] = *(const i32x4*)&wh[(size_t)(col0 + n2) * E + kk + 32 + q2 * 8];
      }
    }
    __syncthreads();

    half8_t ah[2];
#pragma unroll
    for (int t = 0; t < 2; ++t)
      ah[t] = *(const half8_t*)&a_h[(wv * 32 + t * 16 + l15) * LDA + quad * 8];
#pragma unroll
    for (int nt = 0; nt < 6; ++nt) {
      const half8_t bh = *(const half8_t*)&w_h[(nt * 16 + l15) * LDA + quad * 8];
#pragma unroll
      for (int t = 0; t < 2; ++t)
        acc[t][nt] = __builtin_amdgcn_mfma_f32_16x16x32_f16(ah[t], bh, acc[t][nt], 0, 0, 0);
    }
  }

  const float* __restrict__ bias = A.bias[mode];
  _Float16* __restrict__ outp = A.out[mode];
  const float scale = (mode == 0) ? (1.0f / 6.0f) : 1.0f;
#pragma unroll
  for (int nt = 0; nt < 6; ++nt) {
    const int col = col0 + nt * 16 + l15;
    const int h = col / 36, d = col - h * 36;
    const float bc = bias[col];
#pragma unroll
    for (int t = 0; t < 2; ++t) {
#pragma unroll
      for (int r = 0; r < 4; ++r) {
        const int row = row0 + wv * 32 + t * 16 + quad * 4 + r;
        const int b = row >> 11, n = row & (NSEQ - 1);
        const _Float16 val = (_Float16)((acc[t][nt][r] + bc) * scale);
        if (mode == 2) {
          // transposed + pi-interleaved key order
          const int c = n & 63;
          const int np = (n & ~63) | (((c & 15) << 2) | (c >> 4));
          outp[((size_t)(b * NH + h) * 48 + d) * NSEQ + np] = val;
        } else {
          outp[((size_t)(b * NH + h) * NSEQ + n) * 64 + d] = val;
        }
      }
    }
  }
}

// ===========================================================================
// Barrier-free fp16 MFMA flash attention. QB=128 (4 waves x 32 rows, t=2),
// KT=64, SPLIT=4. ALL fragments except P load as half8 DIRECTLY from global:
//   Q/K: [bh][n][64] zero-padded;  V: [bh][48][n'] transposed + pi order.
// Only LDS use: wave-private pbuf for the P C->A relayout -> NO barriers.
// No-max softmax (scores bounded) => linear (acc,sum) split-K partials.
// Dispatch-id swizzle: the 16 q-blocks sharing one (bh,chunk) K/V set map to
// ~2 XCDs (ids equal mod 8 land on the same XCD under round-robin).
// ===========================================================================
#define QB 128
#define KT 64
#define SPLIT 4
#define LDK 64

__device__ __forceinline__ int sw(int row, int col) {
  return row * LDK + ((((col >> 3) ^ row) & 7) << 3) + (col & 7);
}

__global__ __launch_bounds__(256, 5) void attn_kernel(
    const _Float16* __restrict__ q16, const _Float16* __restrict__ k16,
    const _Float16* __restrict__ v16t, float* __restrict__ pacc,
    float* __restrict__ psum) {
  __shared__ __align__(16) _Float16 pbuf[QB * LDK];  // 16 KB

  const int tid = threadIdx.x;
  const int lane = tid & 63;
  const int w = tid >> 6;
  const int quad = lane >> 4;
  const int l15 = lane & 15;

  // id swizzle: id = (x&1) + 2*bh + 64*((x>>1) + 8*chunk)
  const int id = blockIdx.x;
  const int lo = id & 63, hi = id >> 6;
  const int chunk = hi >> 3;
  const int xq = ((hi & 7) << 1) | (lo & 1);  // q-block index 0..15
  const int bh = lo >> 1;
  const int q0 = xq * QB;

  // Q A-fragments direct from global
  const _Float16* qbase = q16 + ((size_t)bh * NSEQ + q0 + w * 32) * 64;
  half8_t qf[2][2];
#pragma unroll
  for (int t = 0; t < 2; ++t)
#pragma unroll
    for (int kc = 0; kc < 2; ++kc)
      qf[t][kc] = *(const half8_t*)&qbase[(t * 16 + l15) * 64 + kc * 32 + quad * 8];

  f32x4 oacc[2][3];
#pragma unroll
  for (int t = 0; t < 2; ++t)
#pragma unroll
    for (int nt = 0; nt < 3; ++nt) oacc[t][nt] = (f32x4){0.f, 0.f, 0.f, 0.f};
  float ssum[2][4] = {{0.f, 0.f, 0.f, 0.f}, {0.f, 0.f, 0.f, 0.f}};

  const _Float16* kbp = k16 + (size_t)bh * NSEQ * 64;
  const _Float16* vbp = v16t + (size_t)bh * 48 * NSEQ;

  const int kk0 = chunk * (NSEQ / SPLIT);
  for (int kb = kk0; kb < kk0 + NSEQ / SPLIT; kb += KT) {
    // ---- QK^T + exp + P-write, per row-stripe t
#pragma unroll
    for (int t = 0; t < 2; ++t) {
      f32x4 sc[4];
#pragma unroll
      for (int s = 0; s < 4; ++s) {
        const _Float16* kr = &kbp[(size_t)(kb + s * 16 + l15) * 64];
        const half8_t kf0 = *(const half8_t*)&kr[quad * 8];
        const half8_t kf1 = *(const half8_t*)&kr[32 + quad * 8];
        f32x4 c0 = __builtin_amdgcn_mfma_f32_16x16x32_f16(
            qf[t][0], kf0, (f32x4){0.f, 0.f, 0.f, 0.f}, 0, 0, 0);
        sc[s] = __builtin_amdgcn_mfma_f32_16x16x32_f16(qf[t][1], kf1, c0, 0, 0, 0);
      }
#pragma unroll
      for (int r = 0; r < 4; ++r) {
        const float p0 = __expf(sc[0][r]);
        const float p1 = __expf(sc[1][r]);
        const float p2 = __expf(sc[2][r]);
        const float p3 = __expf(sc[3][r]);
        ssum[t][r] += (p0 + p1) + (p2 + p3);
        half4_t ph = {(_Float16)p0, (_Float16)p1, (_Float16)p2, (_Float16)p3};
        // pi-position of key s*16+l15 is l15*4+s -> half4 at col l15*4
        *(half4_t*)&pbuf[sw(w * 32 + t * 16 + quad * 4 + r, l15 * 4)] = ph;
      }
    }
    // pbuf rows [32w,32w+32) are wave-private; DS ops in-order within a wave

    // ---- P @ V (V B-fragments direct from global, pi-consistent)
#pragma unroll
    for (int kc = 0; kc < 2; ++kc) {
      half8_t vf[3];
#pragma unroll
      for (int nt = 0; nt < 3; ++nt)
        vf[nt] = *(const half8_t*)&vbp[(size_t)(nt * 16 + l15) * NSEQ + kb + kc * 32 + quad * 8];
#pragma unroll
      for (int t = 0; t < 2; ++t) {
        const half8_t af = *(const half8_t*)&pbuf[sw(w * 32 + t * 16 + l15, kc * 32 + quad * 8)];
#pragma unroll
        for (int nt = 0; nt < 3; ++nt)
          oacc[t][nt] = __builtin_amdgcn_mfma_f32_16x16x32_f16(af, vf[nt], oacc[t][nt], 0, 0, 0);
      }
    }
  }

  // ---- write raw split-K partials
#pragma unroll
  for (int t = 0; t < 2; ++t) {
#pragma unroll
    for (int r = 0; r < 4; ++r) {
      float s = ssum[t][r];
      s += __shfl_xor(s, 1);
      s += __shfl_xor(s, 2);
      s += __shfl_xor(s, 4);
      s += __shfl_xor(s, 8);
      const int row = q0 + w * 32 + t * 16 + quad * 4 + r;
      const size_t gr = (size_t)chunk * (BH * NSEQ) + (size_t)bh * NSEQ + row;
      if (l15 == 0) psum[gr] = s;
#pragma unroll
      for (int nt = 0; nt < 3; ++nt) {
        const int col = nt * 16 + l15;
        if (col < HD) pacc[gr * HD + col] = oacc[t][nt][r];
      }
    }
  }
}

// ===========================================================================
// Combine split-K partials -> pre-split (hi,lo) fp16 input for the O proj
// ===========================================================================
__global__ __launch_bounds__(256) void combine_kernel(
    const float* __restrict__ pacc, const float* __restrict__ psum,
    _Float16* __restrict__ ab_hi, _Float16* __restrict__ ab_lo) {
  const int idx = blockIdx.x * 256 + threadIdx.x;
  if (idx >= BH * NSEQ * HD) return;
  const int gr = idx / HD;
  const int d = idx - gr * HD;

  float a = 0.f, s = 0.f;
#pragma unroll
  for (int c = 0; c < SPLIT; ++c) {
    a += pacc[((size_t)c * (BH * NSEQ) + gr) * HD + d];
    s += psum[(size_t)c * (BH * NSEQ) + gr];
  }
  const float val = a / s;
  const int bh = gr >> 11;
  const int n = gr & (NSEQ - 1);
  const int b = bh >> 3, h = bh & 7;
  const size_t o = ((size_t)(b * NSEQ + n)) * E + h * HD + d;
  const _Float16 hi = (_Float16)val;
  ab_hi[o] = hi;
  ab_lo[o] = (_Float16)(val - (float)hi);
}

// ===========================================================================
// O projection: 2-term (x_hi + x_lo) @ W_hi, fp32 out, tile 128x96, prefetch
// ===========================================================================
__global__ __launch_bounds__(256, 4) void proj_o_kernel(
    const _Float16* __restrict__ xh, const _Float16* __restrict__ xl,
    const _Float16* __restrict__ wh, const float* __restrict__ bias,
    float* __restrict__ out) {
  __shared__ __align__(16) _Float16 a_h[PM * LDA];
  __shared__ __align__(16) _Float16 a_l[PM * LDA];
  __shared__ __align__(16) _Float16 w_h[PN * LDA];

  const int tid = threadIdx.x;
  const int lane = tid & 63, wv = tid >> 6;
  const int quad = lane >> 4, l15 = lane & 15;
  const int row0 = blockIdx.x * PM, col0 = blockIdx.y * PN;

  f32x4 acc[2][6];
#pragma unroll
  for (int t = 0; t < 2; ++t)
#pragma unroll
    for (int nt = 0; nt < 6; ++nt) acc[t][nt] = (f32x4){0.f, 0.f, 0.f, 0.f};

  i32x4 hpre[2], lpre[2], wpre[2];
#pragma unroll
  for (int iu = 0; iu < 2; ++iu) {
    const int i = tid + 256 * iu, r = i >> 2, qd = i & 3;
    hpre[iu] = *(const i32x4*)&xh[(size_t)(row0 + r) * E + qd * 8];
    lpre[iu] = *(const i32x4*)&xl[(size_t)(row0 + r) * E + qd * 8];
  }
  {
    const int n = tid >> 2, qd = tid & 3;
    wpre[0] = *(const i32x4*)&wh[(size_t)(col0 + n) * E + qd * 8];
    if (tid < 128) {
      const int i = tid + 256, n2 = i >> 2, q2 = i & 3;
      wpre[1] = *(const i32x4*)&wh[(size_t)(col0 + n2) * E + q2 * 8];
    }
  }

  for (int kk = 0; kk < E; kk += 32) {
    __syncthreads();
#pragma unroll
    for (int iu = 0; iu < 2; ++iu) {
      const int i = tid + 256 * iu, r = i >> 2, qd = i & 3;
      *(i32x4*)&a_h[r * LDA + qd * 8] = hpre[iu];
      *(i32x4*)&a_l[r * LDA + qd * 8] = lpre[iu];
    }
    {
      const int n = tid >> 2, qd = tid & 3;
      *(i32x4*)&w_h[n * LDA + qd * 8] = wpre[0];
      if (tid < 128) {
        const int i = tid + 256, n2 = i >> 2, q2 = i & 3;
        *(i32x4*)&w_h[n2 * LDA + q2 * 8] = wpre[1];
      }
    }
    if (kk + 32 < E) {
#pragma unroll
      for (int iu = 0; iu < 2; ++iu) {
        const int i = tid + 256 * iu, r = i >> 2, qd = i & 3;
        hpre[iu] = *(const i32x4*)&xh[(size_t)(row0 + r) * E + kk + 32 + qd * 8];
        lpre[iu] = *(const i32x4*)&xl[(size_t)(row0 + r) * E + kk + 32 + qd * 8];
      }
      const int n = tid >> 2, qd = tid & 3;
      wpre[0] = *(const i32x4*)&wh[(size_t)(col0 + n) * E + kk + 32 + qd * 8];
      if (tid < 128) {
        const int i = tid + 256, n2 = i >> 2, q2 = i & 3;
        wpre[1] = *(const i32x4*)&wh[(size_t)(col0 + n2) * E + kk + 32 + q2 * 8];
      }
    }
    __syncthreads();

    half8_t ah[2], al[2];
#pragma unroll
    for (int t = 0; t < 2; ++t) {
      ah[t] = *(const half8_t*)&a_h[(wv * 32 + t * 16 + l15) * LDA + quad * 8];
      al[t] = *(const half8_t*)&a_l[(wv * 32 + t * 16 + l15) * LDA + quad * 8];
    }
#pragma unroll
    for (int nt = 0; nt < 6; ++nt) {
      const half8_t bh = *(const half8_t*)&w_h[(nt * 16 + l15) * LDA + quad * 8];
#pragma unroll
      for (int t = 0; t < 2; ++t) {
        acc[t][nt] = __builtin_amdgcn_mfma_f32_16x16x32_f16(ah[t], bh, acc[t][nt], 0, 0, 0);
        acc[t][nt] = __builtin_amdgcn_mfma_f32_16x16x32_f16(al[t], bh, acc[t][nt], 0, 0, 0);
      }
    }
  }

#pragma unroll
  for (int nt = 0; nt < 6; ++nt) {
    const int col = col0 + nt * 16 + l15;
    const float bc = bias[col];
#pragma unroll
    for (int t = 0; t < 2; ++t) {
#pragma unroll
      for (int r = 0; r < 4; ++r) {
        const int row = row0 + wv * 32 + t * 16 + quad * 4 + r;
        out[(size_t)row * E + col] = acc[t][nt][r] + bc;
      }
    }
  }
}

// ===========================================================================
extern "C" void kernel_launch(void* const* d_in, const int* in_sizes, int n_in,
                              void* d_out, int out_size, void* d_ws,
                              size_t ws_size, hipStream_t stream) {
  const float* query = (const float*)d_in[0];
  const float* key_ = (const float*)d_in[1];
  const float* value = (const float*)d_in[2];
  const float* Wq = (const float*)d_in[3];
  const float* bq = (const float*)d_in[4];
  const float* Wk = (const float*)d_in[5];
  const float* bk = (const float*)d_in[6];
  const float* Wv = (const float*)d_in[7];
  const float* bv = (const float*)d_in[8];
  const float* Wo = (const float*)d_in[9];
  const float* bo = (const float*)d_in[10];
  float* out = (float*)d_out;

  // workspace layout
  _Float16* q16 = (_Float16*)d_ws;                        // BH*NSEQ*64
  _Float16* k16 = q16 + (size_t)BH * NSEQ * 64;           // BH*NSEQ*64
  _Float16* v16t = k16 + (size_t)BH * NSEQ * 64;          // BH*48*NSEQ
  float* pacc = (float*)(v16t + (size_t)BH * 48 * NSEQ);  // SPLIT*BH*NSEQ*HD
  float* psum = pacc + (size_t)SPLIT * BH * NSEQ * HD;    // SPLIT*BH*NSEQ
  _Float16* whalf = (_Float16*)(psum + (size_t)SPLIT * BH * NSEQ);  // 4*E*E
  _Float16* ab_hi = whalf + (size_t)4 * E * E;            // ROWS*E
  _Float16* ab_lo = ab_hi + (size_t)ROWS * E;             // ROWS*E

  // zero q16/k16 (d-padding 36..63) and v16t (rows 36..47 per bh)
  hipMemsetAsync(
      q16, 0,
      ((size_t)2 * BH * NSEQ * 64 + (size_t)BH * 48 * NSEQ) * sizeof(_Float16),
      stream);

  split_w_kernel<<<(4 * E * E) / 256, 256, 0, stream>>>(Wq, Wk, Wv, Wo, whalf);

  QKVArgs qa;
  qa.x[0] = query; qa.x[1] = key_; qa.x[2] = value;
  qa.w[0] = whalf + 0 * (size_t)(E * E);
  qa.w[1] = whalf + 1 * (size_t)(E * E);
  qa.w[2] = whalf + 2 * (size_t)(E * E);
  qa.bias[0] = bq; qa.bias[1] = bk; qa.bias[2] = bv;
  qa.out[0] = q16; qa.out[1] = k16; qa.out[2] = v16t;
  proj_qkv_kernel<<<dim3(ROWS / PM, E / PN, 3), 256, 0, stream>>>(qa);

  attn_kernel<<<dim3((NSEQ / QB) * BH * SPLIT, 1, 1), 256, 0, stream>>>(
      q16, k16, v16t, pacc, psum);

  combine_kernel<<<(BH * NSEQ * HD + 255) / 256, 256, 0, stream>>>(pacc, psum,
                                                                   ab_hi, ab_lo);

  proj_o_kernel<<<dim3(ROWS / PM, E / PN), 256, 0, stream>>>(
      ab_hi, ab_lo, whalf + 3 * (size_t)(E * E), bo, out);
}

// Round 8
// 181.675 us; speedup vs baseline: 1.7273x; 1.7273x over previous
//
#include <hip/hip_runtime.h>

#define E 288
#define NSEQ 2048
#define BATCH 4
#define NH 8
#define HD 36
#define BH (BATCH * NH)      // 32
#define ROWS (BATCH * NSEQ)  // 8192

typedef _Float16 half8_t __attribute__((ext_vector_type(8)));
typedef _Float16 half4_t __attribute__((ext_vector_type(4)));
typedef float f32x4 __attribute__((ext_vector_type(4)));
typedef int i32x4 __attribute__((ext_vector_type(4)));

// XOR-swizzle of 16-B chunks within a 64-half (128 B) row: conflict-free for
// both row-wise b128 staging and column-fragment b128 reads.
__device__ __forceinline__ int sw64(int row, int col) {
  return (row << 6) + ((((col >> 3) ^ row) & 7) << 3) + (col & 7);
}

// async global->LDS, 16 B per lane; LDS dest wave-uniform, lanes spread +16B
__device__ __forceinline__ void gld16(const _Float16* g, _Float16* l) {
  __builtin_amdgcn_global_load_lds(
      (const __attribute__((address_space(1))) void*)g,
      (__attribute__((address_space(3))) void*)l, 16, 0, 0);
}

// 2^x via v_exp_f32 (avoids glibc's __exp2f name)
__device__ __forceinline__ float fexp2(float x) {
  return __builtin_amdgcn_exp2f(x);
}

// ===========================================================================
// split_w: W (fp32, [k][n]) -> transposed fp16: whalf[m][n*E + k]
// ===========================================================================
__global__ __launch_bounds__(256) void split_w_kernel(
    const float* __restrict__ Wq, const float* __restrict__ Wk,
    const float* __restrict__ Wv, const float* __restrict__ Wo,
    _Float16* __restrict__ whalf) {
  const int idx = blockIdx.x * 256 + threadIdx.x;  // 0 .. 4*E*E-1
  const int m = idx / (E * E);
  const int rem = idx - m * (E * E);
  const int k = rem / E, n = rem - k * E;
  const float* W = (m == 0) ? Wq : (m == 1) ? Wk : (m == 2) ? Wv : Wo;
  whalf[(size_t)m * (E * E) + n * E + k] = (_Float16)W[rem];
}

// ===========================================================================
// QKV projection, single-term fp16 MFMA. Tile 128x96, K chunks of 32,
// register prefetch across barriers.
// mode 0 -> q16 [bh][n][64]   (cols 36..63 pre-zeroed by memset; scale folds
//                              D^-0.5 * log2(e) so attn can use exp2)
// mode 1 -> kblk: per (bh, kt) 64x64-half tile at sw64(c, d)   (8 KB tiles)
// mode 2 -> vblk: per (bh, kt) 48x64-half tile at sw64(d, pi(c)) (6 KB tiles)
// Pad regions of kblk/vblk stay 0xAA poison (finite fp16); killed by q16's
// zero pad (K) or the col<36 store mask (V).
// ===========================================================================
#define PM 128
#define PN 96
#define LDA 40  // LDS row stride in halfs

struct QKVArgs {
  const float* x[3];
  const _Float16* w[3];
  const float* bias[3];
  _Float16* out[3];
};

__global__ __launch_bounds__(256, 4) void proj_qkv_kernel(QKVArgs A) {
  __shared__ __align__(16) _Float16 a_h[PM * LDA];
  __shared__ __align__(16) _Float16 w_h[PN * LDA];

  const int tid = threadIdx.x;
  const int lane = tid & 63, wv = tid >> 6;
  const int quad = lane >> 4, l15 = lane & 15;
  const int mode = blockIdx.z;
  const float* __restrict__ x = A.x[mode];
  const _Float16* __restrict__ wh = A.w[mode];
  const int row0 = blockIdx.x * PM, col0 = blockIdx.y * PN;

  f32x4 acc[2][6];
#pragma unroll
  for (int t = 0; t < 2; ++t)
#pragma unroll
    for (int nt = 0; nt < 6; ++nt) acc[t][nt] = (f32x4){0.f, 0.f, 0.f, 0.f};

  float4 apre[4];
  i32x4 wpre[2];
#pragma unroll
  for (int iu = 0; iu < 4; ++iu) {
    const int i = tid + 256 * iu, r = i >> 3, c4 = i & 7;
    apre[iu] = *(const float4*)&x[(size_t)(row0 + r) * E + c4 * 4];
  }
  {
    const int n = tid >> 2, qd = tid & 3;
    wpre[0] = *(const i32x4*)&wh[(size_t)(col0 + n) * E + qd * 8];
    if (tid < 128) {
      const int i = tid + 256, n2 = i >> 2, q2 = i & 3;
      wpre[1] = *(const i32x4*)&wh[(size_t)(col0 + n2) * E + q2 * 8];
    }
  }

  for (int kk = 0; kk < E; kk += 32) {
    __syncthreads();
#pragma unroll
    for (int iu = 0; iu < 4; ++iu) {
      const int i = tid + 256 * iu, r = i >> 3, c4 = i & 7;
      half4_t hv = {(_Float16)apre[iu].x, (_Float16)apre[iu].y,
                    (_Float16)apre[iu].z, (_Float16)apre[iu].w};
      *(half4_t*)&a_h[r * LDA + c4 * 4] = hv;
    }
    {
      const int n = tid >> 2, qd = tid & 3;
      *(i32x4*)&w_h[n * LDA + qd * 8] = wpre[0];
      if (tid < 128) {
        const int i = tid + 256, n2 = i >> 2, q2 = i & 3;
        *(i32x4*)&w_h[n2 * LDA + q2 * 8] = wpre[1];
      }
    }
    if (kk + 32 < E) {
#pragma unroll
      for (int iu = 0; iu < 4; ++iu) {
        const int i = tid + 256 * iu, r = i >> 3, c4 = i & 7;
        apre[iu] = *(const float4*)&x[(size_t)(row0 + r) * E + kk + 32 + c4 * 4];
      }
      const int n = tid >> 2, qd = tid & 3;
      wpre[0] = *(const i32x4*)&wh[(size_t)(col0 + n) * E + kk + 32 + qd * 8];
      if (tid < 128) {
        const int i = tid + 256, n2 = i >> 2, q2 = i & 3;
        wpre[1] = *(const i32x4*)&wh[(size_t)(col0 + n2) * E + kk + 32 + q2 * 8];
      }
    }
    __syncthreads();

    half8_t ah[2];
#pragma unroll
    for (int t = 0; t < 2; ++t)
      ah[t] = *(const half8_t*)&a_h[(wv * 32 + t * 16 + l15) * LDA + quad * 8];
#pragma unroll
    for (int nt = 0; nt < 6; ++nt) {
      const half8_t bh = *(const half8_t*)&w_h[(nt * 16 + l15) * LDA + quad * 8];
#pragma unroll
      for (int t = 0; t < 2; ++t)
        acc[t][nt] = __builtin_amdgcn_mfma_f32_16x16x32_f16(ah[t], bh, acc[t][nt], 0, 0, 0);
    }
  }

  const float* __restrict__ bias = A.bias[mode];
  _Float16* __restrict__ outp = A.out[mode];
  // mode 0: fold D^-0.5 * log2(e) so attention uses exp2 directly
  const float scale = (mode == 0) ? 0.24044917348149868f : 1.0f;
#pragma unroll
  for (int nt = 0; nt < 6; ++nt) {
    const int col = col0 + nt * 16 + l15;
    const int h = col / 36, d = col - h * 36;
    const float bc = bias[col];
#pragma unroll
    for (int t = 0; t < 2; ++t) {
#pragma unroll
      for (int r = 0; r < 4; ++r) {
        const int row = row0 + wv * 32 + t * 16 + quad * 4 + r;
        const int b = row >> 11, n = row & (NSEQ - 1);
        const int bh = b * NH + h;
        const _Float16 val = (_Float16)((acc[t][nt][r] + bc) * scale);
        if (mode == 0) {
          outp[((size_t)bh * NSEQ + n) * 64 + d] = val;
        } else {
          const int kt = n >> 6, c = n & 63;
          if (mode == 1) {
            outp[((size_t)bh * 32 + kt) * 4096 + sw64(c, d)] = val;
          } else {
            const int pc = ((c & 15) << 2) | (c >> 4);
            outp[((size_t)bh * 32 + kt) * 3072 + sw64(d, pc)] = val;
          }
        }
      }
    }
  }
}

// ===========================================================================
// fp16 MFMA flash attention. QB=128 (4 waves x 32 rows), KT=64, SPLIT=4.
// K/V tiles are pre-swizzled 8/6-KB global blocks staged via async
// global_load_lds into double-buffered LDS; ONE barrier per tile (stage of
// tile it+1 issued after the barrier, hidden behind tile it's compute).
// Q fragments direct from global (read once). No-max softmax via exp2
// (Q pre-scaled by log2e/6) => linear (acc,sum) split-K partials.
// XCD-affine id swizzle: 16 q-blocks sharing one (bh,chunk) K/V set have
// ids congruent mod 8 -> one XCD's L2 under round-robin placement.
// ===========================================================================
#define QB 128
#define KT 64
#define SPLIT 4

__device__ __forceinline__ void stage_tile(const _Float16* kg, const _Float16* vg,
                                           _Float16* kb, _Float16* vb, int w,
                                           int lane) {
  // K tile: 8 KB = 8 segments of 1 KB (64 lanes x 16 B)
#pragma unroll
  for (int seg = w; seg < 8; seg += 4)
    gld16(kg + seg * 512 + lane * 8, kb + seg * 512);
  // V tile: 6 KB = 6 segments
  for (int seg = w; seg < 6; seg += 4)
    gld16(vg + seg * 512 + lane * 8, vb + seg * 512);
}

__global__ __launch_bounds__(256, 3) void attn_kernel(
    const _Float16* __restrict__ q16, const _Float16* __restrict__ kblk,
    const _Float16* __restrict__ vblk, float* __restrict__ pacc,
    float* __restrict__ psum) {
  __shared__ __align__(16) _Float16 kbuf[2][KT * 64];  // 2 x 8 KB
  __shared__ __align__(16) _Float16 vbuf[2][48 * 64];  // 2 x 6 KB
  __shared__ __align__(16) _Float16 pbuf[QB * 64];     // 16 KB

  const int tid = threadIdx.x;
  const int lane = tid & 63;
  const int w = tid >> 6;
  const int quad = lane >> 4;
  const int l15 = lane & 15;

  // id = xcd + 8*qb + 128*g ; (bh,chunk) = g*8+xcd
  const int id = blockIdx.x;
  const int xcd = id & 7;
  const int qb = (id >> 3) & 15;
  const int g = id >> 7;
  const int bhc = g * 8 + xcd;
  const int bh = bhc >> 2;
  const int chunk = bhc & 3;
  const int q0 = qb * QB;

  // Q A-fragments direct from global (zero-padded d>=36)
  const _Float16* qbase = q16 + ((size_t)bh * NSEQ + q0 + w * 32) * 64;
  half8_t qf[2][2];
#pragma unroll
  for (int t = 0; t < 2; ++t)
#pragma unroll
    for (int kc = 0; kc < 2; ++kc)
      qf[t][kc] = *(const half8_t*)&qbase[(t * 16 + l15) * 64 + kc * 32 + quad * 8];

  f32x4 oacc[2][3];
#pragma unroll
  for (int t = 0; t < 2; ++t)
#pragma unroll
    for (int nt = 0; nt < 3; ++nt) oacc[t][nt] = (f32x4){0.f, 0.f, 0.f, 0.f};
  float ssum[2][4] = {{0.f, 0.f, 0.f, 0.f}, {0.f, 0.f, 0.f, 0.f}};

  const int t0 = chunk * 8;  // base tile index (8 tiles per chunk)
  const _Float16* kbase = kblk + ((size_t)bh * 32 + t0) * 4096;
  const _Float16* vbase = vblk + ((size_t)bh * 32 + t0) * 3072;

  stage_tile(kbase, vbase, kbuf[0], vbuf[0], w, lane);

  for (int it = 0; it < 8; ++it) {
    const int cur = it & 1;
    __syncthreads();  // drains stage(it); orders prior reads of buf[cur^1]
    if (it + 1 < 8)
      stage_tile(kbase + (it + 1) * 4096, vbase + (it + 1) * 3072,
                 kbuf[cur ^ 1], vbuf[cur ^ 1], w, lane);

    // ---- QK^T + exp2 + P-write (pi key order), per row-stripe t
#pragma unroll
    for (int t = 0; t < 2; ++t) {
      f32x4 sc[4];
#pragma unroll
      for (int s = 0; s < 4; ++s) {
        const half8_t kf0 = *(const half8_t*)&kbuf[cur][sw64(s * 16 + l15, quad * 8)];
        const half8_t kf1 = *(const half8_t*)&kbuf[cur][sw64(s * 16 + l15, 32 + quad * 8)];
        f32x4 c0 = __builtin_amdgcn_mfma_f32_16x16x32_f16(
            qf[t][0], kf0, (f32x4){0.f, 0.f, 0.f, 0.f}, 0, 0, 0);
        sc[s] = __builtin_amdgcn_mfma_f32_16x16x32_f16(qf[t][1], kf1, c0, 0, 0, 0);
      }
#pragma unroll
      for (int r = 0; r < 4; ++r) {
        const float p0 = fexp2(sc[0][r]);
        const float p1 = fexp2(sc[1][r]);
        const float p2 = fexp2(sc[2][r]);
        const float p3 = fexp2(sc[3][r]);
        ssum[t][r] += (p0 + p1) + (p2 + p3);
        half4_t ph = {(_Float16)p0, (_Float16)p1, (_Float16)p2, (_Float16)p3};
        *(half4_t*)&pbuf[sw64(w * 32 + t * 16 + quad * 4 + r, l15 * 4)] = ph;
      }
    }
    // pbuf rows [32w,32w+32) wave-private; DS ops in-order within a wave

    // ---- P @ V
#pragma unroll
    for (int kc = 0; kc < 2; ++kc) {
      half8_t vf[3];
#pragma unroll
      for (int nt = 0; nt < 3; ++nt)
        vf[nt] = *(const half8_t*)&vbuf[cur][sw64(nt * 16 + l15, kc * 32 + quad * 8)];
#pragma unroll
      for (int t = 0; t < 2; ++t) {
        const half8_t af = *(const half8_t*)&pbuf[sw64(w * 32 + t * 16 + l15, kc * 32 + quad * 8)];
#pragma unroll
        for (int nt = 0; nt < 3; ++nt)
          oacc[t][nt] = __builtin_amdgcn_mfma_f32_16x16x32_f16(af, vf[nt], oacc[t][nt], 0, 0, 0);
      }
    }
  }

  // ---- write raw split-K partials
#pragma unroll
  for (int t = 0; t < 2; ++t) {
#pragma unroll
    for (int r = 0; r < 4; ++r) {
      float s = ssum[t][r];
      s += __shfl_xor(s, 1);
      s += __shfl_xor(s, 2);
      s += __shfl_xor(s, 4);
      s += __shfl_xor(s, 8);
      const int row = q0 + w * 32 + t * 16 + quad * 4 + r;
      const size_t gr = (size_t)chunk * (BH * NSEQ) + (size_t)bh * NSEQ + row;
      if (l15 == 0) psum[gr] = s;
#pragma unroll
      for (int nt = 0; nt < 3; ++nt) {
        const int col = nt * 16 + l15;
        if (col < HD) pacc[gr * HD + col] = oacc[t][nt][r];
      }
    }
  }
}

// ===========================================================================
// Combine split-K partials -> pre-split (hi,lo) fp16 input for the O proj
// ===========================================================================
__global__ __launch_bounds__(256) void combine_kernel(
    const float* __restrict__ pacc, const float* __restrict__ psum,
    _Float16* __restrict__ ab_hi, _Float16* __restrict__ ab_lo) {
  const int idx = blockIdx.x * 256 + threadIdx.x;
  if (idx >= BH * NSEQ * HD) return;
  const int gr = idx / HD;
  const int d = idx - gr * HD;

  float a = 0.f, s = 0.f;
#pragma unroll
  for (int c = 0; c < SPLIT; ++c) {
    a += pacc[((size_t)c * (BH * NSEQ) + gr) * HD + d];
    s += psum[(size_t)c * (BH * NSEQ) + gr];
  }
  const float val = a / s;
  const int bh = gr >> 11;
  const int n = gr & (NSEQ - 1);
  const int b = bh >> 3, h = bh & 7;
  const size_t o = ((size_t)(b * NSEQ + n)) * E + h * HD + d;
  const _Float16 hi = (_Float16)val;
  ab_hi[o] = hi;
  ab_lo[o] = (_Float16)(val - (float)hi);
}

// ===========================================================================
// O projection: 2-term (x_hi + x_lo) @ W_hi, fp32 out, tile 128x96, prefetch
// ===========================================================================
__global__ __launch_bounds__(256, 4) void proj_o_kernel(
    const _Float16* __restrict__ xh, const _Float16* __restrict__ xl,
    const _Float16* __restrict__ wh, const float* __restrict__ bias,
    float* __restrict__ out) {
  __shared__ __align__(16) _Float16 a_h[PM * LDA];
  __shared__ __align__(16) _Float16 a_l[PM * LDA];
  __shared__ __align__(16) _Float16 w_h[PN * LDA];

  const int tid = threadIdx.x;
  const int lane = tid & 63, wv = tid >> 6;
  const int quad = lane >> 4, l15 = lane & 15;
  const int row0 = blockIdx.x * PM, col0 = blockIdx.y * PN;

  f32x4 acc[2][6];
#pragma unroll
  for (int t = 0; t < 2; ++t)
#pragma unroll
    for (int nt = 0; nt < 6; ++nt) acc[t][nt] = (f32x4){0.f, 0.f, 0.f, 0.f};

  i32x4 hpre[2], lpre[2], wpre[2];
#pragma unroll
  for (int iu = 0; iu < 2; ++iu) {
    const int i = tid + 256 * iu, r = i >> 2, qd = i & 3;
    hpre[iu] = *(const i32x4*)&xh[(size_t)(row0 + r) * E + qd * 8];
    lpre[iu] = *(const i32x4*)&xl[(size_t)(row0 + r) * E + qd * 8];
  }
  {
    const int n = tid >> 2, qd = tid & 3;
    wpre[0] = *(const i32x4*)&wh[(size_t)(col0 + n) * E + qd * 8];
    if (tid < 128) {
      const int i = tid + 256, n2 = i >> 2, q2 = i & 3;
      wpre[1] = *(const i32x4*)&wh[(size_t)(col0 + n2) * E + q2 * 8];
    }
  }

  for (int kk = 0; kk < E; kk += 32) {
    __syncthreads();
#pragma unroll
    for (int iu = 0; iu < 2; ++iu) {
      const int i = tid + 256 * iu, r = i >> 2, qd = i & 3;
      *(i32x4*)&a_h[r * LDA + qd * 8] = hpre[iu];
      *(i32x4*)&a_l[r * LDA + qd * 8] = lpre[iu];
    }
    {
      const int n = tid >> 2, qd = tid & 3;
      *(i32x4*)&w_h[n * LDA + qd * 8] = wpre[0];
      if (tid < 128) {
        const int i = tid + 256, n2 = i >> 2, q2 = i & 3;
        *(i32x4*)&w_h[n2 * LDA + q2 * 8] = wpre[1];
      }
    }
    if (kk + 32 < E) {
#pragma unroll
      for (int iu = 0; iu < 2; ++iu) {
        const int i = tid + 256 * iu, r = i >> 2, qd = i & 3;
        hpre[iu] = *(const i32x4*)&xh[(size_t)(row0 + r) * E + kk + 32 + qd * 8];
        lpre[iu] = *(const i32x4*)&xl[(size_t)(row0 + r) * E + kk + 32 + qd * 8];
      }
      const int n = tid >> 2, qd = tid & 3;
      wpre[0] = *(const i32x4*)&wh[(size_t)(col0 + n) * E + kk + 32 + qd * 8];
      if (tid < 128) {
        const int i = tid + 256, n2 = i >> 2, q2 = i & 3;
        wpre[1] = *(const i32x4*)&wh[(size_t)(col0 + n2) * E + kk + 32 + q2 * 8];
      }
    }
    __syncthreads();

    half8_t ah[2], al[2];
#pragma unroll
    for (int t = 0; t < 2; ++t) {
      ah[t] = *(const half8_t*)&a_h[(wv * 32 + t * 16 + l15) * LDA + quad * 8];
      al[t] = *(const half8_t*)&a_l[(wv * 32 + t * 16 + l15) * LDA + quad * 8];
    }
#pragma unroll
    for (int nt = 0; nt < 6; ++nt) {
      const half8_t bh = *(const half8_t*)&w_h[(nt * 16 + l15) * LDA + quad * 8];
#pragma unroll
      for (int t = 0; t < 2; ++t) {
        acc[t][nt] = __builtin_amdgcn_mfma_f32_16x16x32_f16(ah[t], bh, acc[t][nt], 0, 0, 0);
        acc[t][nt] = __builtin_amdgcn_mfma_f32_16x16x32_f16(al[t], bh, acc[t][nt], 0, 0, 0);
      }
    }
  }

#pragma unroll
  for (int nt = 0; nt < 6; ++nt) {
    const int col = col0 + nt * 16 + l15;
    const float bc = bias[col];
#pragma unroll
    for (int t = 0; t < 2; ++t) {
#pragma unroll
      for (int r = 0; r < 4; ++r) {
        const int row = row0 + wv * 32 + t * 16 + quad * 4 + r;
        out[(size_t)row * E + col] = acc[t][nt][r] + bc;
      }
    }
  }
}

// ===========================================================================
extern "C" void kernel_launch(void* const* d_in, const int* in_sizes, int n_in,
                              void* d_out, int out_size, void* d_ws,
                              size_t ws_size, hipStream_t stream) {
  const float* query = (const float*)d_in[0];
  const float* key_ = (const float*)d_in[1];
  const float* value = (const float*)d_in[2];
  const float* Wq = (const float*)d_in[3];
  const float* bq = (const float*)d_in[4];
  const float* Wk = (const float*)d_in[5];
  const float* bk = (const float*)d_in[6];
  const float* Wv = (const float*)d_in[7];
  const float* bv = (const float*)d_in[8];
  const float* Wo = (const float*)d_in[9];
  const float* bo = (const float*)d_in[10];
  float* out = (float*)d_out;

  // workspace layout (halfs/floats)
  _Float16* q16 = (_Float16*)d_ws;                        // BH*NSEQ*64
  _Float16* kblk = q16 + (size_t)BH * NSEQ * 64;          // BH*32*4096
  _Float16* vblk = kblk + (size_t)BH * 32 * 4096;         // BH*32*3072
  float* pacc = (float*)(vblk + (size_t)BH * 32 * 3072);  // SPLIT*BH*NSEQ*HD
  float* psum = pacc + (size_t)SPLIT * BH * NSEQ * HD;    // SPLIT*BH*NSEQ
  _Float16* whalf = (_Float16*)(psum + (size_t)SPLIT * BH * NSEQ);  // 4*E*E
  _Float16* ab_hi = whalf + (size_t)4 * E * E;            // ROWS*E
  _Float16* ab_lo = ab_hi + (size_t)ROWS * E;             // ROWS*E

  // zero q16 (d-pad 36..63 must be 0 to kill kblk's poison pad in QK^T)
  (void)hipMemsetAsync(q16, 0, (size_t)BH * NSEQ * 64 * sizeof(_Float16),
                       stream);

  split_w_kernel<<<(4 * E * E) / 256, 256, 0, stream>>>(Wq, Wk, Wv, Wo, whalf);

  QKVArgs qa;
  qa.x[0] = query; qa.x[1] = key_; qa.x[2] = value;
  qa.w[0] = whalf + 0 * (size_t)(E * E);
  qa.w[1] = whalf + 1 * (size_t)(E * E);
  qa.w[2] = whalf + 2 * (size_t)(E * E);
  qa.bias[0] = bq; qa.bias[1] = bk; qa.bias[2] = bv;
  qa.out[0] = q16; qa.out[1] = kblk; qa.out[2] = vblk;
  proj_qkv_kernel<<<dim3(ROWS / PM, E / PN, 3), 256, 0, stream>>>(qa);

  attn_kernel<<<dim3((NSEQ / QB) * BH * SPLIT), 256, 0, stream>>>(
      q16, kblk, vblk, pacc, psum);

  combine_kernel<<<(BH * NSEQ * HD + 255) / 256, 256, 0, stream>>>(pacc, psum,
                                                                   ab_hi, ab_lo);

  proj_o_kernel<<<dim3(ROWS / PM, E / PN), 256, 0, stream>>>(
      ab_hi, ab_lo, whalf + 3 * (size_t)(E * E), bo, out);
}

// Round 9
// 172.776 us; speedup vs baseline: 1.8163x; 1.0515x over previous
//
#include <hip/hip_runtime.h>

#define E 288
#define NSEQ 2048
#define BATCH 4
#define NH 8
#define HD 36
#define BH (BATCH * NH)      // 32
#define ROWS (BATCH * NSEQ)  // 8192
#define BHN (BH * NSEQ)      // 65536

typedef _Float16 half8_t __attribute__((ext_vector_type(8)));
typedef _Float16 half4_t __attribute__((ext_vector_type(4)));
typedef float f32x4 __attribute__((ext_vector_type(4)));
typedef int i32x4 __attribute__((ext_vector_type(4)));

// --- swizzle for 64-half rows (attn K/V tiles; unchanged from R8) ---------
__device__ __forceinline__ int sw64(int row, int col) {
  return (row << 6) + ((((col >> 3) ^ row) & 7) << 3) + (col & 7);
}

// --- packed-tile swizzle for T x 32-half tiles (proj A/W tiles) -----------
// two 32-half rows packed per 128-B row'; XOR granule swizzle.
// b128 fragment reads (16 lanes, rows base+l15, fixed quad) hit each 16-B
// bank-position exactly twice -> conflict-free (2-way is free).
__device__ __forceinline__ int toff(int r, int k) {
  const int rp = r >> 1;
  const int g = (((r & 1) << 2) + (k >> 3)) ^ (rp & 7);
  return (rp << 6) + ((g & 7) << 3) + (k & 7);
}

// async global->LDS, 16 B per lane; LDS dest wave-uniform, lanes +16 B
__device__ __forceinline__ void gld16(const _Float16* g, _Float16* l) {
  __builtin_amdgcn_global_load_lds(
      (const __attribute__((address_space(1))) void*)g,
      (__attribute__((address_space(3))) void*)l, 16, 0, 0);
}

__device__ __forceinline__ float fexp2(float x) {
  return __builtin_amdgcn_exp2f(x);
}

// ===========================================================================
// prep: (a) x (q/k/v inputs) fp32 -> fp16 pre-swizzled 128x32 tile blocks
//       (b) W fp32 [k][n] -> fp16 pre-swizzled 96x32 tile blocks (transposed)
//       (c) zero q16 (d-pad 36..63 must be 0)
// x16blk[mode]: [RB 64][C 9] 4096-half tiles.  wblk: [(m*3+CT)*9+C] 3072-half.
// ===========================================================================
#define XBLK 6912   // 3*8192*72 / 256
#define WBLK 1296   // 4*288*288 / 256
#define QZBLK 2048  // BH*NSEQ*64/8 / 256

__global__ __launch_bounds__(256) void prep_kernel(
    const float* __restrict__ xq, const float* __restrict__ xk,
    const float* __restrict__ xv, const float* __restrict__ Wq,
    const float* __restrict__ Wk, const float* __restrict__ Wv,
    const float* __restrict__ Wo, _Float16* __restrict__ x16blk,
    _Float16* __restrict__ wblk, _Float16* __restrict__ q16) {
  const int bid = blockIdx.x;
  const int tid = threadIdx.x;
  if (bid < XBLK) {
    const int i = bid * 256 + tid;  // (mode, row, k4)
    const int mode = i / (ROWS * 72);
    const int rem = i - mode * (ROWS * 72);
    const int row = rem / 72, k4 = rem - row * 72;
    const float* x = (mode == 0) ? xq : (mode == 1) ? xk : xv;
    const float4 v = *(const float4*)&x[(size_t)row * E + k4 * 4];
    half4_t h = {(_Float16)v.x, (_Float16)v.y, (_Float16)v.z, (_Float16)v.w};
    _Float16* dst = x16blk + (size_t)mode * (64 * 9 * 4096) +
                    ((((row >> 7) * 9 + (k4 >> 3))) << 12) +
                    toff(row & 127, (k4 & 7) * 4);
    *(half4_t*)dst = h;
  } else if (bid < XBLK + WBLK) {
    const int j = (bid - XBLK) * 256 + tid;  // (m, k, n)
    const int m = j / (E * E);
    const int rem = j - m * (E * E);
    const int k = rem / E, n = rem - k * E;
    const float* W = (m == 0) ? Wq : (m == 1) ? Wk : (m == 2) ? Wv : Wo;
    wblk[(size_t)((m * 3 + n / 96) * 9 + (k >> 5)) * 3072 +
         toff(n % 96, k & 31)] = (_Float16)W[(size_t)k * E + n];
  } else {
    const int j = (bid - XBLK - WBLK) * 256 + tid;
    ((i32x4*)q16)[j] = (i32x4){0, 0, 0, 0};
  }
}

// ===========================================================================
// QKV projection: async-staged, double-buffered, ONE barrier per K-chunk.
// PM=128 x PN=96, 9 chunks of K=32. A from x16blk, W from wblk (both
// pre-swizzled; staging is verbatim gld16). Outputs (epilogue as R8):
// mode 0 -> q16 [bh][n][64] (pad pre-zeroed; scale folds D^-0.5*log2 e)
// mode 1 -> kblk per-(bh,kt) 64x64 tiles at sw64(c,d)
// mode 2 -> vblk per-(bh,kt) 48x64 tiles at sw64(d,pi(c))
// ===========================================================================
#define PM 128
#define PN 96

struct QKVArgs {
  const _Float16* x[3];
  const float* bias[3];
  _Float16* out[3];
};

__global__ __launch_bounds__(256, 4) void proj_qkv_kernel(
    QKVArgs A, const _Float16* __restrict__ wblk) {
  __shared__ __align__(16) _Float16 abuf[2][4096];
  __shared__ __align__(16) _Float16 wbuf[2][3072];

  const int tid = threadIdx.x;
  const int lane = tid & 63, w = tid >> 6;
  const int quad = lane >> 4, l15 = lane & 15;
  const int mode = blockIdx.z;
  const int RB = blockIdx.x, CT = blockIdx.y;
  const _Float16* __restrict__ ablk = A.x[mode] + (size_t)RB * 9 * 4096;
  const _Float16* __restrict__ wb = wblk + (size_t)(mode * 3 + CT) * 9 * 3072;

  f32x4 acc[2][6];
#pragma unroll
  for (int t = 0; t < 2; ++t)
#pragma unroll
    for (int nt = 0; nt < 6; ++nt) acc[t][nt] = (f32x4){0.f, 0.f, 0.f, 0.f};

  // stage chunk 0
#pragma unroll
  for (int seg = w; seg < 8; seg += 4)
    gld16(ablk + seg * 512 + lane * 8, abuf[0] + seg * 512);
  for (int seg = w; seg < 6; seg += 4)
    gld16(wb + seg * 512 + lane * 8, wbuf[0] + seg * 512);

  for (int C = 0; C < 9; ++C) {
    const int cur = C & 1;
    __syncthreads();  // drains stage(C); orders prior reads of buf[cur^1]
    if (C + 1 < 9) {
#pragma unroll
      for (int seg = w; seg < 8; seg += 4)
        gld16(ablk + (C + 1) * 4096 + seg * 512 + lane * 8,
              abuf[cur ^ 1] + seg * 512);
      for (int seg = w; seg < 6; seg += 4)
        gld16(wb + (C + 1) * 3072 + seg * 512 + lane * 8,
              wbuf[cur ^ 1] + seg * 512);
    }
    half8_t ah[2];
#pragma unroll
    for (int t = 0; t < 2; ++t)
      ah[t] = *(const half8_t*)&abuf[cur][toff(w * 32 + t * 16 + l15, quad * 8)];
#pragma unroll
    for (int nt = 0; nt < 6; ++nt) {
      const half8_t bf = *(const half8_t*)&wbuf[cur][toff(nt * 16 + l15, quad * 8)];
#pragma unroll
      for (int t = 0; t < 2; ++t)
        acc[t][nt] = __builtin_amdgcn_mfma_f32_16x16x32_f16(ah[t], bf, acc[t][nt], 0, 0, 0);
    }
  }

  const float* __restrict__ bias = A.bias[mode];
  _Float16* __restrict__ outp = A.out[mode];
  const float scale = (mode == 0) ? 0.24044917348149868f : 1.0f;
  const int row0 = RB * PM, col0 = CT * PN;
#pragma unroll
  for (int nt = 0; nt < 6; ++nt) {
    const int col = col0 + nt * 16 + l15;
    const int h = col / 36, d = col - h * 36;
    const float bc = bias[col];
#pragma unroll
    for (int t = 0; t < 2; ++t) {
#pragma unroll
      for (int r = 0; r < 4; ++r) {
        const int row = row0 + w * 32 + t * 16 + quad * 4 + r;
        const int b = row >> 11, n = row & (NSEQ - 1);
        const int bh = b * NH + h;
        const _Float16 val = (_Float16)((acc[t][nt][r] + bc) * scale);
        if (mode == 0) {
          outp[((size_t)bh * NSEQ + n) * 64 + d] = val;
        } else {
          const int kt = n >> 6, c = n & 63;
          if (mode == 1) {
            outp[((size_t)bh * 32 + kt) * 4096 + sw64(c, d)] = val;
          } else {
            const int pc = ((c & 15) << 2) | (c >> 4);
            outp[((size_t)bh * 32 + kt) * 3072 + sw64(d, pc)] = val;
          }
        }
      }
    }
  }
}

// ===========================================================================
// fp16 MFMA flash attention (R8 structure; pacc now fp16).
// ===========================================================================
#define QB 128
#define KT 64
#define SPLIT 4

__device__ __forceinline__ void stage_tile(const _Float16* kg, const _Float16* vg,
                                           _Float16* kb, _Float16* vb, int w,
                                           int lane) {
#pragma unroll
  for (int seg = w; seg < 8; seg += 4)
    gld16(kg + seg * 512 + lane * 8, kb + seg * 512);
  for (int seg = w; seg < 6; seg += 4)
    gld16(vg + seg * 512 + lane * 8, vb + seg * 512);
}

__global__ __launch_bounds__(256, 3) void attn_kernel(
    const _Float16* __restrict__ q16, const _Float16* __restrict__ kblk,
    const _Float16* __restrict__ vblk, _Float16* __restrict__ pacc16,
    float* __restrict__ psum) {
  __shared__ __align__(16) _Float16 kbuf[2][KT * 64];
  __shared__ __align__(16) _Float16 vbuf[2][48 * 64];
  __shared__ __align__(16) _Float16 pbuf[QB * 64];

  const int tid = threadIdx.x;
  const int lane = tid & 63;
  const int w = tid >> 6;
  const int quad = lane >> 4;
  const int l15 = lane & 15;

  const int id = blockIdx.x;
  const int xcd = id & 7;
  const int qb = (id >> 3) & 15;
  const int g = id >> 7;
  const int bhc = g * 8 + xcd;
  const int bh = bhc >> 2;
  const int chunk = bhc & 3;
  const int q0 = qb * QB;

  const _Float16* qbase = q16 + ((size_t)bh * NSEQ + q0 + w * 32) * 64;
  half8_t qf[2][2];
#pragma unroll
  for (int t = 0; t < 2; ++t)
#pragma unroll
    for (int kc = 0; kc < 2; ++kc)
      qf[t][kc] = *(const half8_t*)&qbase[(t * 16 + l15) * 64 + kc * 32 + quad * 8];

  f32x4 oacc[2][3];
#pragma unroll
  for (int t = 0; t < 2; ++t)
#pragma unroll
    for (int nt = 0; nt < 3; ++nt) oacc[t][nt] = (f32x4){0.f, 0.f, 0.f, 0.f};
  float ssum[2][4] = {{0.f, 0.f, 0.f, 0.f}, {0.f, 0.f, 0.f, 0.f}};

  const int t0 = chunk * 8;
  const _Float16* kbase = kblk + ((size_t)bh * 32 + t0) * 4096;
  const _Float16* vbase = vblk + ((size_t)bh * 32 + t0) * 3072;

  stage_tile(kbase, vbase, kbuf[0], vbuf[0], w, lane);

  for (int it = 0; it < 8; ++it) {
    const int cur = it & 1;
    __syncthreads();
    if (it + 1 < 8)
      stage_tile(kbase + (it + 1) * 4096, vbase + (it + 1) * 3072,
                 kbuf[cur ^ 1], vbuf[cur ^ 1], w, lane);

#pragma unroll
    for (int t = 0; t < 2; ++t) {
      f32x4 sc[4];
#pragma unroll
      for (int s = 0; s < 4; ++s) {
        const half8_t kf0 = *(const half8_t*)&kbuf[cur][sw64(s * 16 + l15, quad * 8)];
        const half8_t kf1 = *(const half8_t*)&kbuf[cur][sw64(s * 16 + l15, 32 + quad * 8)];
        f32x4 c0 = __builtin_amdgcn_mfma_f32_16x16x32_f16(
            qf[t][0], kf0, (f32x4){0.f, 0.f, 0.f, 0.f}, 0, 0, 0);
        sc[s] = __builtin_amdgcn_mfma_f32_16x16x32_f16(qf[t][1], kf1, c0, 0, 0, 0);
      }
#pragma unroll
      for (int r = 0; r < 4; ++r) {
        const float p0 = fexp2(sc[0][r]);
        const float p1 = fexp2(sc[1][r]);
        const float p2 = fexp2(sc[2][r]);
        const float p3 = fexp2(sc[3][r]);
        ssum[t][r] += (p0 + p1) + (p2 + p3);
        half4_t ph = {(_Float16)p0, (_Float16)p1, (_Float16)p2, (_Float16)p3};
        *(half4_t*)&pbuf[sw64(w * 32 + t * 16 + quad * 4 + r, l15 * 4)] = ph;
      }
    }

#pragma unroll
    for (int kc = 0; kc < 2; ++kc) {
      half8_t vf[3];
#pragma unroll
      for (int nt = 0; nt < 3; ++nt)
        vf[nt] = *(const half8_t*)&vbuf[cur][sw64(nt * 16 + l15, kc * 32 + quad * 8)];
#pragma unroll
      for (int t = 0; t < 2; ++t) {
        const half8_t af = *(const half8_t*)&pbuf[sw64(w * 32 + t * 16 + l15, kc * 32 + quad * 8)];
#pragma unroll
        for (int nt = 0; nt < 3; ++nt)
          oacc[t][nt] = __builtin_amdgcn_mfma_f32_16x16x32_f16(af, vf[nt], oacc[t][nt], 0, 0, 0);
      }
    }
  }

#pragma unroll
  for (int t = 0; t < 2; ++t) {
#pragma unroll
    for (int r = 0; r < 4; ++r) {
      float s = ssum[t][r];
      s += __shfl_xor(s, 1);
      s += __shfl_xor(s, 2);
      s += __shfl_xor(s, 4);
      s += __shfl_xor(s, 8);
      const int row = q0 + w * 32 + t * 16 + quad * 4 + r;
      const size_t gr = (size_t)chunk * BHN + (size_t)bh * NSEQ + row;
      if (l15 == 0) psum[gr] = s;
#pragma unroll
      for (int nt = 0; nt < 3; ++nt) {
        const int col = nt * 16 + l15;
        if (col < HD) pacc16[gr * HD + col] = (_Float16)oacc[t][nt][r];
      }
    }
  }
}

// ===========================================================================
// Combine split-K partials -> (hi,lo) fp16 in proj_o's pre-swizzled 64x32
// tile-block format: abh/abl [RB 128][C 9] 2048-half tiles.
// ===========================================================================
__global__ __launch_bounds__(256) void combine_kernel(
    const _Float16* __restrict__ pacc16, const float* __restrict__ psum,
    _Float16* __restrict__ abh, _Float16* __restrict__ abl) {
  const int idx = blockIdx.x * 256 + threadIdx.x;  // (gr, d4), 65536*9
  if (idx >= BHN * 9) return;
  const int gr = idx / 9;
  const int d4 = idx - gr * 9;

  float a[4] = {0.f, 0.f, 0.f, 0.f};
  float s = 0.f;
#pragma unroll
  for (int c = 0; c < SPLIT; ++c) {
    const half4_t p = *(const half4_t*)&pacc16[((size_t)c * BHN + gr) * HD + d4 * 4];
#pragma unroll
    for (int j = 0; j < 4; ++j) a[j] += (float)p[j];
    s += psum[(size_t)c * BHN + gr];
  }
  const float inv = 1.0f / s;
  const int bh = gr >> 11;
  const int n = gr & (NSEQ - 1);
  const int b = bh >> 3, h = bh & 7;
  const int row = b * NSEQ + n;
  const int col = h * 36 + d4 * 4;

  half4_t hv, lv;
#pragma unroll
  for (int j = 0; j < 4; ++j) {
    const float val = a[j] * inv;
    const _Float16 hi = (_Float16)val;
    hv[j] = hi;
    lv[j] = (_Float16)(val - (float)hi);
  }
  const size_t o = (size_t)((row >> 6) * 9 + (col >> 5)) * 2048 + toff(row & 63, col & 31);
  *(half4_t*)&abh[o] = hv;
  *(half4_t*)&abl[o] = lv;
}

// ===========================================================================
// O projection: 2-term (x_hi + x_lo) @ W_hi, async-staged, 1 barrier/chunk.
// PM=64 x PN=96 -> 384 blocks, all resident. fp32 out.
// ===========================================================================
__global__ __launch_bounds__(256, 4) void proj_o_kernel(
    const _Float16* __restrict__ abh, const _Float16* __restrict__ abl,
    const _Float16* __restrict__ wblk_o, const float* __restrict__ bias,
    float* __restrict__ out) {
  __shared__ __align__(16) _Float16 hbuf[2][2048];
  __shared__ __align__(16) _Float16 lbuf[2][2048];
  __shared__ __align__(16) _Float16 wbuf[2][3072];

  const int tid = threadIdx.x;
  const int lane = tid & 63, w = tid >> 6;
  const int quad = lane >> 4, l15 = lane & 15;
  const int RB = blockIdx.x, CT = blockIdx.y;
  const _Float16* __restrict__ hblk = abh + (size_t)RB * 9 * 2048;
  const _Float16* __restrict__ lblk = abl + (size_t)RB * 9 * 2048;
  const _Float16* __restrict__ wb = wblk_o + (size_t)CT * 9 * 3072;

  f32x4 acc[6];
#pragma unroll
  for (int nt = 0; nt < 6; ++nt) acc[nt] = (f32x4){0.f, 0.f, 0.f, 0.f};

  // stage chunk 0 (A hi: 4 segs, A lo: 4 segs, W: 6 segs)
  gld16(hblk + w * 512 + lane * 8, hbuf[0] + w * 512);
  gld16(lblk + w * 512 + lane * 8, lbuf[0] + w * 512);
  for (int seg = w; seg < 6; seg += 4)
    gld16(wb + seg * 512 + lane * 8, wbuf[0] + seg * 512);

  for (int C = 0; C < 9; ++C) {
    const int cur = C & 1;
    __syncthreads();
    if (C + 1 < 9) {
      gld16(hblk + (C + 1) * 2048 + w * 512 + lane * 8, hbuf[cur ^ 1] + w * 512);
      gld16(lblk + (C + 1) * 2048 + w * 512 + lane * 8, lbuf[cur ^ 1] + w * 512);
      for (int seg = w; seg < 6; seg += 4)
        gld16(wb + (C + 1) * 3072 + seg * 512 + lane * 8, wbuf[cur ^ 1] + seg * 512);
    }
    const half8_t ah = *(const half8_t*)&hbuf[cur][toff(w * 16 + l15, quad * 8)];
    const half8_t al = *(const half8_t*)&lbuf[cur][toff(w * 16 + l15, quad * 8)];
#pragma unroll
    for (int nt = 0; nt < 6; ++nt) {
      const half8_t bf = *(const half8_t*)&wbuf[cur][toff(nt * 16 + l15, quad * 8)];
      acc[nt] = __builtin_amdgcn_mfma_f32_16x16x32_f16(ah, bf, acc[nt], 0, 0, 0);
      acc[nt] = __builtin_amdgcn_mfma_f32_16x16x32_f16(al, bf, acc[nt], 0, 0, 0);
    }
  }

#pragma unroll
  for (int nt = 0; nt < 6; ++nt) {
    const int col = CT * PN + nt * 16 + l15;
    const float bc = bias[col];
#pragma unroll
    for (int r = 0; r < 4; ++r) {
      const int row = RB * 64 + w * 16 + quad * 4 + r;
      out[(size_t)row * E + col] = acc[nt][r] + bc;
    }
  }
}

// ===========================================================================
extern "C" void kernel_launch(void* const* d_in, const int* in_sizes, int n_in,
                              void* d_out, int out_size, void* d_ws,
                              size_t ws_size, hipStream_t stream) {
  const float* query = (const float*)d_in[0];
  const float* key_ = (const float*)d_in[1];
  const float* value = (const float*)d_in[2];
  const float* Wq = (const float*)d_in[3];
  const float* bq = (const float*)d_in[4];
  const float* Wk = (const float*)d_in[5];
  const float* bk = (const float*)d_in[6];
  const float* Wv = (const float*)d_in[7];
  const float* bv = (const float*)d_in[8];
  const float* Wo = (const float*)d_in[9];
  const float* bo = (const float*)d_in[10];
  float* out = (float*)d_out;

  // workspace layout (halfs, then floats)
  _Float16* q16 = (_Float16*)d_ws;                    // BH*NSEQ*64   = 4.19M
  _Float16* kblk = q16 + (size_t)BH * NSEQ * 64;      // BH*32*4096   = 4.19M
  _Float16* vblk = kblk + (size_t)BH * 32 * 4096;     // BH*32*3072   = 3.15M
  _Float16* x16blk = vblk + (size_t)BH * 32 * 3072;   // 3*64*9*4096  = 7.08M
  _Float16* wblk = x16blk + (size_t)3 * 64 * 9 * 4096;  // 4*3*9*3072 = 332k
  _Float16* abh = wblk + (size_t)4 * 3 * 9 * 3072;    // 128*9*2048   = 2.36M
  _Float16* abl = abh + (size_t)128 * 9 * 2048;       // 2.36M
  _Float16* pacc16 = abl + (size_t)128 * 9 * 2048;    // 4*BHN*36     = 9.44M
  float* psum = (float*)(pacc16 + (size_t)SPLIT * BHN * HD);  // 4*BHN fp32

  prep_kernel<<<XBLK + WBLK + QZBLK, 256, 0, stream>>>(
      query, key_, value, Wq, Wk, Wv, Wo, x16blk, wblk, q16);

  QKVArgs qa;
  qa.x[0] = x16blk + 0 * (size_t)(64 * 9 * 4096);
  qa.x[1] = x16blk + 1 * (size_t)(64 * 9 * 4096);
  qa.x[2] = x16blk + 2 * (size_t)(64 * 9 * 4096);
  qa.bias[0] = bq; qa.bias[1] = bk; qa.bias[2] = bv;
  qa.out[0] = q16; qa.out[1] = kblk; qa.out[2] = vblk;
  proj_qkv_kernel<<<dim3(ROWS / PM, E / PN, 3), 256, 0, stream>>>(qa, wblk);

  attn_kernel<<<dim3((NSEQ / QB) * BH * SPLIT), 256, 0, stream>>>(
      q16, kblk, vblk, pacc16, psum);

  combine_kernel<<<(BHN * 9) / 256, 256, 0, stream>>>(pacc16, psum, abh, abl);

  proj_o_kernel<<<dim3(ROWS / 64, E / PN), 256, 0, stream>>>(
      abh, abl, wblk + (size_t)3 * 3 * 9 * 3072, bo, out);
}

// Round 10
// 169.744 us; speedup vs baseline: 1.8487x; 1.0179x over previous
//
#include <hip/hip_runtime.h>

#define E 288
#define NSEQ 2048
#define BATCH 4
#define NH 8
#define HD 36
#define BH (BATCH * NH)      // 32
#define ROWS (BATCH * NSEQ)  // 8192
#define BHN (BH * NSEQ)      // 65536

typedef _Float16 half8_t __attribute__((ext_vector_type(8)));
typedef _Float16 half4_t __attribute__((ext_vector_type(4)));
typedef float f32x4 __attribute__((ext_vector_type(4)));
typedef int i32x4 __attribute__((ext_vector_type(4)));

// --- swizzle for 64-half rows (attn K/V tiles) ----------------------------
__device__ __forceinline__ int sw64(int row, int col) {
  return (row << 6) + ((((col >> 3) ^ row) & 7) << 3) + (col & 7);
}

// --- packed-tile swizzle for T x 32-half tiles (proj A/W tiles) -----------
__device__ __forceinline__ int toff(int r, int k) {
  const int rp = r >> 1;
  const int g = (((r & 1) << 2) + (k >> 3)) ^ (rp & 7);
  return (rp << 6) + ((g & 7) << 3) + (k & 7);
}

// async global->LDS, 16 B per lane; LDS dest wave-uniform, lanes +16 B
__device__ __forceinline__ void gld16(const _Float16* g, _Float16* l) {
  __builtin_amdgcn_global_load_lds(
      (const __attribute__((address_space(1))) void*)g,
      (__attribute__((address_space(3))) void*)l, 16, 0, 0);
}

__device__ __forceinline__ float fexp2(float x) {
  return __builtin_amdgcn_exp2f(x);
}

// ===========================================================================
// prep: (a) W fp32 [k][n] -> fp16 pre-swizzled 96x32 tile blocks (transposed)
//       (b) zero q16 (d-pad 36..63 must be 0)
// ===========================================================================
#define WBLK 1296   // 4*288*288 / 256
#define QZBLK 2048  // BH*NSEQ*64/8 / 256

__global__ __launch_bounds__(256) void prep_kernel(
    const float* __restrict__ Wq, const float* __restrict__ Wk,
    const float* __restrict__ Wv, const float* __restrict__ Wo,
    _Float16* __restrict__ wblk, _Float16* __restrict__ q16) {
  const int bid = blockIdx.x;
  const int tid = threadIdx.x;
  if (bid < WBLK) {
    const int j = bid * 256 + tid;  // (m, k, n)
    const int m = j / (E * E);
    const int rem = j - m * (E * E);
    const int k = rem / E, n = rem - k * E;
    const float* W = (m == 0) ? Wq : (m == 1) ? Wk : (m == 2) ? Wv : Wo;
    wblk[(size_t)((m * 3 + n / 96) * 9 + (k >> 5)) * 3072 +
         toff(n % 96, k & 31)] = (_Float16)W[(size_t)k * E + n];
  } else {
    const int j = (bid - WBLK) * 256 + tid;
    ((i32x4*)q16)[j] = (i32x4){0, 0, 0, 0};
  }
}

// ===========================================================================
// QKV projection: A read directly from fp32 x (float4, register-prefetched,
// converted during LDS write); W staged via gld16 from pre-swizzled wblk.
// Double-buffered, ONE barrier per K-chunk; all VMEM issued post-barrier.
// PM=128 x PN=96, 9 chunks of K=32. Outputs (epilogue as R8/R9):
// mode 0 -> q16 [bh][n][64]; mode 1 -> kblk sw64(c,d); mode 2 -> vblk
// sw64(d,pi(c)).
// ===========================================================================
#define PM 128
#define PN 96

struct QKVArgs {
  const float* x[3];
  const float* bias[3];
  _Float16* out[3];
};

__global__ __launch_bounds__(256, 4) void proj_qkv_kernel(
    QKVArgs A, const _Float16* __restrict__ wblk) {
  __shared__ __align__(16) _Float16 abuf[2][4096];
  __shared__ __align__(16) _Float16 wbuf[2][3072];

  const int tid = threadIdx.x;
  const int lane = tid & 63, w = tid >> 6;
  const int quad = lane >> 4, l15 = lane & 15;
  const int mode = blockIdx.z;
  const int RB = blockIdx.x, CT = blockIdx.y;
  const float* __restrict__ x = A.x[mode];
  const _Float16* __restrict__ wb = wblk + (size_t)(mode * 3 + CT) * 9 * 3072;
  const int row0 = RB * PM;

  float4 apre[4];
  // load A chunk C into regs
  auto loadA = [&](int C) {
#pragma unroll
    for (int iu = 0; iu < 4; ++iu) {
      const int i = tid + 256 * iu, r = i >> 3, c4 = i & 7;
      apre[iu] = *(const float4*)&x[(size_t)(row0 + r) * E + C * 32 + c4 * 4];
    }
  };
  auto writeA = [&](_Float16* dst) {
#pragma unroll
    for (int iu = 0; iu < 4; ++iu) {
      const int i = tid + 256 * iu, r = i >> 3, c4 = i & 7;
      half4_t h = {(_Float16)apre[iu].x, (_Float16)apre[iu].y,
                   (_Float16)apre[iu].z, (_Float16)apre[iu].w};
      *(half4_t*)&dst[toff(r, c4 * 4)] = h;
    }
  };

  f32x4 acc[2][6];
#pragma unroll
  for (int t = 0; t < 2; ++t)
#pragma unroll
    for (int nt = 0; nt < 6; ++nt) acc[t][nt] = (f32x4){0.f, 0.f, 0.f, 0.f};

  // pre-loop: A(0) -> abuf[0]; W(0) gld16; prefetch A(1)
  loadA(0);
  writeA(abuf[0]);
  for (int seg = w; seg < 6; seg += 4)
    gld16(wb + seg * 512 + lane * 8, wbuf[0] + seg * 512);
  loadA(1);

  for (int C = 0; C < 9; ++C) {
    const int cur = C & 1;
    __syncthreads();  // drains abuf[cur] writes + wbuf[cur] gld16
    if (C + 1 < 9) {
      for (int seg = w; seg < 6; seg += 4)
        gld16(wb + (C + 1) * 3072 + seg * 512 + lane * 8,
              wbuf[cur ^ 1] + seg * 512);
      writeA(abuf[cur ^ 1]);
      if (C + 2 < 9) loadA(C + 2);
    }
    half8_t ah[2];
#pragma unroll
    for (int t = 0; t < 2; ++t)
      ah[t] = *(const half8_t*)&abuf[cur][toff(w * 32 + t * 16 + l15, quad * 8)];
#pragma unroll
    for (int nt = 0; nt < 6; ++nt) {
      const half8_t bf = *(const half8_t*)&wbuf[cur][toff(nt * 16 + l15, quad * 8)];
#pragma unroll
      for (int t = 0; t < 2; ++t)
        acc[t][nt] = __builtin_amdgcn_mfma_f32_16x16x32_f16(ah[t], bf, acc[t][nt], 0, 0, 0);
    }
  }

  const float* __restrict__ bias = A.bias[mode];
  _Float16* __restrict__ outp = A.out[mode];
  const float scale = (mode == 0) ? 0.24044917348149868f : 1.0f;
  const int col0 = CT * PN;
#pragma unroll
  for (int nt = 0; nt < 6; ++nt) {
    const int col = col0 + nt * 16 + l15;
    const int h = col / 36, d = col - h * 36;
    const float bc = bias[col];
#pragma unroll
    for (int t = 0; t < 2; ++t) {
#pragma unroll
      for (int r = 0; r < 4; ++r) {
        const int row = row0 + w * 32 + t * 16 + quad * 4 + r;
        const int b = row >> 11, n = row & (NSEQ - 1);
        const int bh = b * NH + h;
        const _Float16 val = (_Float16)((acc[t][nt][r] + bc) * scale);
        if (mode == 0) {
          outp[((size_t)bh * NSEQ + n) * 64 + d] = val;
        } else {
          const int kt = n >> 6, c = n & 63;
          if (mode == 1) {
            outp[((size_t)bh * 32 + kt) * 4096 + sw64(c, d)] = val;
          } else {
            const int pc = ((c & 15) << 2) | (c >> 4);
            outp[((size_t)bh * 32 + kt) * 3072 + sw64(d, pc)] = val;
          }
        }
      }
    }
  }
}

// ===========================================================================
// fp16 MFMA flash attention (R8/R9 structure; per-wave 16-row P buffer ->
// LDS 36 KB -> 4 blocks/CU).
// ===========================================================================
#define QB 128
#define KT 64
#define SPLIT 4

__device__ __forceinline__ void stage_tile(const _Float16* kg, const _Float16* vg,
                                           _Float16* kb, _Float16* vb, int w,
                                           int lane) {
#pragma unroll
  for (int seg = w; seg < 8; seg += 4)
    gld16(kg + seg * 512 + lane * 8, kb + seg * 512);
  for (int seg = w; seg < 6; seg += 4)
    gld16(vg + seg * 512 + lane * 8, vb + seg * 512);
}

__global__ __launch_bounds__(256, 4) void attn_kernel(
    const _Float16* __restrict__ q16, const _Float16* __restrict__ kblk,
    const _Float16* __restrict__ vblk, _Float16* __restrict__ pacc16,
    float* __restrict__ psum) {
  __shared__ __align__(16) _Float16 kbuf[2][KT * 64];  // 16 KB
  __shared__ __align__(16) _Float16 vbuf[2][48 * 64];  // 12 KB
  __shared__ __align__(16) _Float16 pbuf[4][16 * 64];  // 8 KB (per-wave stripe)

  const int tid = threadIdx.x;
  const int lane = tid & 63;
  const int w = tid >> 6;
  const int quad = lane >> 4;
  const int l15 = lane & 15;

  const int id = blockIdx.x;
  const int xcd = id & 7;
  const int qb = (id >> 3) & 15;
  const int g = id >> 7;
  const int bhc = g * 8 + xcd;
  const int bh = bhc >> 2;
  const int chunk = bhc & 3;
  const int q0 = qb * QB;

  const _Float16* qbase = q16 + ((size_t)bh * NSEQ + q0 + w * 32) * 64;
  half8_t qf[2][2];
#pragma unroll
  for (int t = 0; t < 2; ++t)
#pragma unroll
    for (int kc = 0; kc < 2; ++kc)
      qf[t][kc] = *(const half8_t*)&qbase[(t * 16 + l15) * 64 + kc * 32 + quad * 8];

  f32x4 oacc[2][3];
#pragma unroll
  for (int t = 0; t < 2; ++t)
#pragma unroll
    for (int nt = 0; nt < 3; ++nt) oacc[t][nt] = (f32x4){0.f, 0.f, 0.f, 0.f};
  float ssum[2][4] = {{0.f, 0.f, 0.f, 0.f}, {0.f, 0.f, 0.f, 0.f}};

  const int t0 = chunk * 8;
  const _Float16* kbase = kblk + ((size_t)bh * 32 + t0) * 4096;
  const _Float16* vbase = vblk + ((size_t)bh * 32 + t0) * 3072;

  stage_tile(kbase, vbase, kbuf[0], vbuf[0], w, lane);

  for (int it = 0; it < 8; ++it) {
    const int cur = it & 1;
    __syncthreads();
    if (it + 1 < 8)
      stage_tile(kbase + (it + 1) * 4096, vbase + (it + 1) * 3072,
                 kbuf[cur ^ 1], vbuf[cur ^ 1], w, lane);

    // hoist V fragments (shared across both row stripes)
    half8_t vf[2][3];
#pragma unroll
    for (int kc = 0; kc < 2; ++kc)
#pragma unroll
      for (int nt = 0; nt < 3; ++nt)
        vf[kc][nt] = *(const half8_t*)&vbuf[cur][sw64(nt * 16 + l15, kc * 32 + quad * 8)];

#pragma unroll
    for (int t = 0; t < 2; ++t) {
      f32x4 sc[4];
#pragma unroll
      for (int s = 0; s < 4; ++s) {
        const half8_t kf0 = *(const half8_t*)&kbuf[cur][sw64(s * 16 + l15, quad * 8)];
        const half8_t kf1 = *(const half8_t*)&kbuf[cur][sw64(s * 16 + l15, 32 + quad * 8)];
        f32x4 c0 = __builtin_amdgcn_mfma_f32_16x16x32_f16(
            qf[t][0], kf0, (f32x4){0.f, 0.f, 0.f, 0.f}, 0, 0, 0);
        sc[s] = __builtin_amdgcn_mfma_f32_16x16x32_f16(qf[t][1], kf1, c0, 0, 0, 0);
      }
#pragma unroll
      for (int r = 0; r < 4; ++r) {
        const float p0 = fexp2(sc[0][r]);
        const float p1 = fexp2(sc[1][r]);
        const float p2 = fexp2(sc[2][r]);
        const float p3 = fexp2(sc[3][r]);
        ssum[t][r] += (p0 + p1) + (p2 + p3);
        half4_t ph = {(_Float16)p0, (_Float16)p1, (_Float16)p2, (_Float16)p3};
        *(half4_t*)&pbuf[w][sw64(quad * 4 + r, l15 * 4)] = ph;
      }
      // PV for stripe t (pbuf[w] wave-private; DS in-order per wave)
#pragma unroll
      for (int kc = 0; kc < 2; ++kc) {
        const half8_t af = *(const half8_t*)&pbuf[w][sw64(l15, kc * 32 + quad * 8)];
#pragma unroll
        for (int nt = 0; nt < 3; ++nt)
          oacc[t][nt] = __builtin_amdgcn_mfma_f32_16x16x32_f16(af, vf[kc][nt], oacc[t][nt], 0, 0, 0);
      }
    }
  }

#pragma unroll
  for (int t = 0; t < 2; ++t) {
#pragma unroll
    for (int r = 0; r < 4; ++r) {
      float s = ssum[t][r];
      s += __shfl_xor(s, 1);
      s += __shfl_xor(s, 2);
      s += __shfl_xor(s, 4);
      s += __shfl_xor(s, 8);
      const int row = q0 + w * 32 + t * 16 + quad * 4 + r;
      const size_t gr = (size_t)chunk * BHN + (size_t)bh * NSEQ + row;
      if (l15 == 0) psum[gr] = s;
#pragma unroll
      for (int nt = 0; nt < 3; ++nt) {
        const int col = nt * 16 + l15;
        if (col < HD) pacc16[gr * HD + col] = (_Float16)oacc[t][nt][r];
      }
    }
  }
}

// ===========================================================================
// Combine split-K partials -> (hi,lo) fp16 in proj_o's pre-swizzled 64x32
// tile-block format: abh/abl [RB 128][C 9] 2048-half tiles.
// ===========================================================================
__global__ __launch_bounds__(256) void combine_kernel(
    const _Float16* __restrict__ pacc16, const float* __restrict__ psum,
    _Float16* __restrict__ abh, _Float16* __restrict__ abl) {
  const int idx = blockIdx.x * 256 + threadIdx.x;  // (gr, d4), 65536*9
  if (idx >= BHN * 9) return;
  const int gr = idx / 9;
  const int d4 = idx - gr * 9;

  float a[4] = {0.f, 0.f, 0.f, 0.f};
  float s = 0.f;
#pragma unroll
  for (int c = 0; c < SPLIT; ++c) {
    const half4_t p = *(const half4_t*)&pacc16[((size_t)c * BHN + gr) * HD + d4 * 4];
#pragma unroll
    for (int j = 0; j < 4; ++j) a[j] += (float)p[j];
    s += psum[(size_t)c * BHN + gr];
  }
  const float inv = 1.0f / s;
  const int bh = gr >> 11;
  const int n = gr & (NSEQ - 1);
  const int b = bh >> 3, h = bh & 7;
  const int row = b * NSEQ + n;
  const int col = h * 36 + d4 * 4;

  half4_t hv, lv;
#pragma unroll
  for (int j = 0; j < 4; ++j) {
    const float val = a[j] * inv;
    const _Float16 hi = (_Float16)val;
    hv[j] = hi;
    lv[j] = (_Float16)(val - (float)hi);
  }
  const size_t o = (size_t)((row >> 6) * 9 + (col >> 5)) * 2048 + toff(row & 63, col & 31);
  *(half4_t*)&abh[o] = hv;
  *(half4_t*)&abl[o] = lv;
}

// ===========================================================================
// O projection: 2-term (x_hi + x_lo) @ W_hi, async-staged, 1 barrier/chunk.
// PM=64 x PN=96 -> 384 blocks. fp32 out.
// ===========================================================================
__global__ __launch_bounds__(256, 4) void proj_o_kernel(
    const _Float16* __restrict__ abh, const _Float16* __restrict__ abl,
    const _Float16* __restrict__ wblk_o, const float* __restrict__ bias,
    float* __restrict__ out) {
  __shared__ __align__(16) _Float16 hbuf[2][2048];
  __shared__ __align__(16) _Float16 lbuf[2][2048];
  __shared__ __align__(16) _Float16 wbuf[2][3072];

  const int tid = threadIdx.x;
  const int lane = tid & 63, w = tid >> 6;
  const int quad = lane >> 4, l15 = lane & 15;
  const int RB = blockIdx.x, CT = blockIdx.y;
  const _Float16* __restrict__ hblk = abh + (size_t)RB * 9 * 2048;
  const _Float16* __restrict__ lblk = abl + (size_t)RB * 9 * 2048;
  const _Float16* __restrict__ wb = wblk_o + (size_t)CT * 9 * 3072;

  f32x4 acc[6];
#pragma unroll
  for (int nt = 0; nt < 6; ++nt) acc[nt] = (f32x4){0.f, 0.f, 0.f, 0.f};

  gld16(hblk + w * 512 + lane * 8, hbuf[0] + w * 512);
  gld16(lblk + w * 512 + lane * 8, lbuf[0] + w * 512);
  for (int seg = w; seg < 6; seg += 4)
    gld16(wb + seg * 512 + lane * 8, wbuf[0] + seg * 512);

  for (int C = 0; C < 9; ++C) {
    const int cur = C & 1;
    __syncthreads();
    if (C + 1 < 9) {
      gld16(hblk + (C + 1) * 2048 + w * 512 + lane * 8, hbuf[cur ^ 1] + w * 512);
      gld16(lblk + (C + 1) * 2048 + w * 512 + lane * 8, lbuf[cur ^ 1] + w * 512);
      for (int seg = w; seg < 6; seg += 4)
        gld16(wb + (C + 1) * 3072 + seg * 512 + lane * 8, wbuf[cur ^ 1] + seg * 512);
    }
    const half8_t ah = *(const half8_t*)&hbuf[cur][toff(w * 16 + l15, quad * 8)];
    const half8_t al = *(const half8_t*)&lbuf[cur][toff(w * 16 + l15, quad * 8)];
#pragma unroll
    for (int nt = 0; nt < 6; ++nt) {
      const half8_t bf = *(const half8_t*)&wbuf[cur][toff(nt * 16 + l15, quad * 8)];
      acc[nt] = __builtin_amdgcn_mfma_f32_16x16x32_f16(ah, bf, acc[nt], 0, 0, 0);
      acc[nt] = __builtin_amdgcn_mfma_f32_16x16x32_f16(al, bf, acc[nt], 0, 0, 0);
    }
  }

#pragma unroll
  for (int nt = 0; nt < 6; ++nt) {
    const int col = CT * PN + nt * 16 + l15;
    const float bc = bias[col];
#pragma unroll
    for (int r = 0; r < 4; ++r) {
      const int row = RB * 64 + w * 16 + quad * 4 + r;
      out[(size_t)row * E + col] = acc[nt][r] + bc;
    }
  }
}

// ===========================================================================
extern "C" void kernel_launch(void* const* d_in, const int* in_sizes, int n_in,
                              void* d_out, int out_size, void* d_ws,
                              size_t ws_size, hipStream_t stream) {
  const float* query = (const float*)d_in[0];
  const float* key_ = (const float*)d_in[1];
  const float* value = (const float*)d_in[2];
  const float* Wq = (const float*)d_in[3];
  const float* bq = (const float*)d_in[4];
  const float* Wk = (const float*)d_in[5];
  const float* bk = (const float*)d_in[6];
  const float* Wv = (const float*)d_in[7];
  const float* bv = (const float*)d_in[8];
  const float* Wo = (const float*)d_in[9];
  const float* bo = (const float*)d_in[10];
  float* out = (float*)d_out;

  // workspace layout
  _Float16* q16 = (_Float16*)d_ws;                    // BH*NSEQ*64
  _Float16* kblk = q16 + (size_t)BH * NSEQ * 64;      // BH*32*4096
  _Float16* vblk = kblk + (size_t)BH * 32 * 4096;     // BH*32*3072
  _Float16* wblk = vblk + (size_t)BH * 32 * 3072;     // 4*3*9*3072
  _Float16* abh = wblk + (size_t)4 * 3 * 9 * 3072;    // 128*9*2048
  _Float16* abl = abh + (size_t)128 * 9 * 2048;       // 128*9*2048
  _Float16* pacc16 = abl + (size_t)128 * 9 * 2048;    // SPLIT*BHN*36
  float* psum = (float*)(pacc16 + (size_t)SPLIT * BHN * HD);  // SPLIT*BHN

  prep_kernel<<<WBLK + QZBLK, 256, 0, stream>>>(Wq, Wk, Wv, Wo, wblk, q16);

  QKVArgs qa;
  qa.x[0] = query; qa.x[1] = key_; qa.x[2] = value;
  qa.bias[0] = bq; qa.bias[1] = bk; qa.bias[2] = bv;
  qa.out[0] = q16; qa.out[1] = kblk; qa.out[2] = vblk;
  proj_qkv_kernel<<<dim3(ROWS / PM, E / PN, 3), 256, 0, stream>>>(qa, wblk);

  attn_kernel<<<dim3((NSEQ / QB) * BH * SPLIT), 256, 0, stream>>>(
      q16, kblk, vblk, pacc16, psum);

  combine_kernel<<<(BHN * 9) / 256, 256, 0, stream>>>(pacc16, psum, abh, abl);

  proj_o_kernel<<<dim3(ROWS / 64, E / PN), 256, 0, stream>>>(
      abh, abl, wblk + (size_t)3 * 3 * 9 * 3072, bo, out);
}